// Round 13
// baseline (129.076 us; speedup 1.0000x reference)
//
#include <hip/hip_runtime.h>

#define HH 260
#define WW 346
#define CC 1212            // real channel count (pred layout)
#define CP 1280            // padded compact space: [0,640) pol0, [640,1280) pol1
#define HALF 640
#define NA 606             // active channels per polarity (260 + 346)
#define BB 16
#define TT 4096
#define INV_TEMP (1.0f/256.0f)
#define KCH 256            // chunks per batch
#define LCH 16             // TT / KCH
#define NG 16              // groups per batch
#define GSZ 16             // chunks per group
#define GLEN (GSZ * LCH)   // 256
#define NJ 10              // compact registers per polarity set (640/64)

// v += DPP-permuted(v); permutation stays within a 16-lane row -> VALU pipe, no LDS
template <int CTRL>
__device__ __forceinline__ float dpp_add(float v) {
    const int t = __builtin_amdgcn_update_dpp(0, __float_as_int(v), CTRL, 0xF, 0xF, true);
    return v + __int_as_float(t);
}
__device__ __forceinline__ float wave_sum(float v) {
    v = dpp_add<0xB1>(v);    // quad_perm [1,0,3,2]  (xor1)
    v = dpp_add<0x4E>(v);    // quad_perm [2,3,0,1]  (xor2)
    v = dpp_add<0x124>(v);   // row_ror:4
    v = dpp_add<0x128>(v);   // row_ror:8
    v += __shfl_xor(v, 16);  // DS
    v += __shfl_xor(v, 32);  // DS
    return v;
}

// ---------------- Phase 1: per-chunk local state (zero carry), 4 chunks/block ----------------
__global__ __launch_bounds__(256) void p1_local(const float* __restrict__ target,
                                                float* __restrict__ Lbuf) {
    const int blk = blockIdx.x;            // BB*KCH/4
    const int b = blk >> 6;
    const int k0 = (blk & 63) << 2;
    const int tid = threadIdx.x;
    const int w = tid >> 6, lane = tid & 63;
    const int k = k0 + w;
    const int a = k * LCH;

    __shared__ float tg[4][LCH][4];
    __shared__ float tnextS[4];
    tg[tid >> 6][(tid >> 2) & 15][tid & 3] =
        target[((size_t)b * TT + k0 * LCH) * 4 + tid];
    if (tid < 4) {
        const int kk = k0 + tid;
        tnextS[tid] = (kk < KCH - 1) ? target[((size_t)b * TT + (kk + 1) * LCH) * 4] : 0.0f;
    }
    __syncthreads();

    float s0[NJ], s1[NJ];
#pragma unroll
    for (int j = 0; j < NJ; ++j) { s0[j] = 0.f; s1[j] = 0.f; }

    for (int li = LCH - 1; li >= 0; --li) {
        const int i = a + li;
        const float ti = tg[w][li][0];
        const float tn = (li == LCH - 1) ? tnextS[w] : tg[w][li + 1][0];
        const float d = (i >= TT - 1) ? 0.0f : __expf(-(tn - ti) * INV_TEMP);
        const int y = (int)tg[w][li][1], x = (int)tg[w][li][2], p = (int)tg[w][li][3];
        const int uy = y, ux = 260 + x;
        if (p == 0) {
#pragma unroll
            for (int j = 0; j < NJ; ++j) {
                const int u = lane + 64 * j;
                const float add = (u == uy ? 1.f : 0.f) + (u == ux ? 1.f : 0.f);
                s0[j] = fmaf(s0[j], d, add);
                s1[j] *= d;
            }
        } else {
#pragma unroll
            for (int j = 0; j < NJ; ++j) {
                const int u = lane + 64 * j;
                const float add = (u == uy ? 1.f : 0.f) + (u == ux ? 1.f : 0.f);
                s1[j] = fmaf(s1[j], d, add);
                s0[j] *= d;
            }
        }
    }
    float* __restrict__ out = Lbuf + (size_t)(b * KCH + k) * CP;
#pragma unroll
    for (int j = 0; j < NJ; ++j) {
        out[lane + 64 * j] = s0[j];
        out[HALF + lane + 64 * j] = s1[j];
    }
}

// ------- Phase 2a: within-group (16 chunks) suffix combine -------
__global__ __launch_bounds__(256) void p2a(const float* __restrict__ target,
                                           const float* __restrict__ Lbuf,
                                           float* __restrict__ LCin,
                                           float* __restrict__ GroupL) {
    const int blk = blockIdx.x;            // BB*NG*5
    const int ct = blk % 5;
    const int bg = blk / 5;                // b*NG + g
    const int b = bg >> 4, g = bg & 15;
    const int c = ct * 256 + threadIdx.x;  // < CP

    float carry = 0.f;
#pragma unroll
    for (int kk = GSZ - 1; kk >= 0; --kk) {
        const int k = g * GSZ + kk;
        const size_t idx = ((size_t)(b * KCH + k)) * CP + c;
        LCin[idx] = carry;
        float P = 0.f;
        if (k < KCH - 1) {
            const float ta = target[((size_t)b * TT + k * LCH) * 4];
            const float te = target[((size_t)b * TT + (k + 1) * LCH) * 4];
            P = __expf(-(te - ta) * INV_TEMP);
        }
        carry = fmaf(P, carry, Lbuf[idx]);
    }
    GroupL[(size_t)bg * CP + c] = carry;
}

// ------- Phase 2b: super-scan across 16 groups (preloaded) -------
__global__ __launch_bounds__(256) void p2b(const float* __restrict__ target,
                                           const float* __restrict__ GroupL,
                                           float* __restrict__ SC) {
    const int blk = blockIdx.x;            // BB*5
    const int ct = blk % 5;
    const int b = blk / 5;
    const int c = ct * 256 + threadIdx.x;

    float Gv[NG], GP[NG];
#pragma unroll
    for (int g = 0; g < NG; ++g)
        Gv[g] = GroupL[((size_t)(b * NG + g)) * CP + c];
#pragma unroll
    for (int g = 0; g < NG; ++g) {
        if (g < NG - 1) {
            const float ta = target[((size_t)b * TT + g * GLEN) * 4];
            const float te = target[((size_t)b * TT + (g + 1) * GLEN) * 4];
            GP[g] = __expf(-(te - ta) * INV_TEMP);
        } else GP[g] = 0.f;
    }
    float carry = 0.f;
#pragma unroll
    for (int g = NG - 1; g >= 0; --g) {
        SC[((size_t)(b * NG + g)) * CP + c] = carry;
        carry = fmaf(GP[g], carry, Gv[g]);
    }
}

// ------- Phase 3: replay + fused loss, POLARITY-PLANE SPLIT; DPP-hybrid reduction -------
__global__ __launch_bounds__(256, 8) void p3_loss(const float* __restrict__ pred,
                                                  const float* __restrict__ target,
                                                  const float* __restrict__ LCin,
                                                  const float* __restrict__ SC,
                                                  double* __restrict__ partials) {
    const int blk = blockIdx.x;            // BB*KCH/4
    const int q = blockIdx.y;              // plane/polarity this wave serves
    const int b = blk >> 6;
    const int k0 = (blk & 63) << 2;
    const int tid = threadIdx.x;
    const int w = tid >> 6, lane = tid & 63;
    const int k = k0 + w;
    const int g = k >> 4;
    const int a = k * LCH;

    __shared__ float4 tg4[4][LCH];         // one ds_read_b128 per step
    __shared__ float tnextS[4];
    if (tid < 64) {
        const float4* __restrict__ tgl =
            (const float4*)(target + ((size_t)b * TT + k0 * LCH) * 4);
        ((float4*)tg4)[tid] = tgl[tid];
    }
    if (tid < 4) {
        const int kk = k0 + tid;
        tnextS[tid] = (kk < KCH - 1) ? target[((size_t)b * TT + (kk + 1) * LCH) * 4] : 0.0f;
    }
    __syncthreads();

    float Qk = 0.f;
    if (g < NG - 1) {
        const float tge = target[((size_t)b * TT + (g + 1) * GLEN) * 4];
        const float tk1 = target[((size_t)b * TT + (k + 1) * LCH) * 4];
        Qk = __expf(-(tge - tk1) * INV_TEMP);
    }

    const float* __restrict__ lc = LCin + (size_t)(b * KCH + k) * CP + q * HALF;
    const float* __restrict__ sc = SC + ((size_t)(b * NG + g)) * CP + q * HALF;
    float s[NJ];
#pragma unroll
    for (int j = 0; j < NJ; ++j) {
        const int u = lane + 64 * j;
        s[j] = fmaf(Qk, sc[u], lc[u]);
    }

    double lacc = 0.0;
    float tnext_run = tnextS[w];           // t_{i+1}, carried across iterations
    for (int li = LCH - 1; li >= 0; --li) {
        const int i = a + li;
        const float4 tv = tg4[w][li];
        const float ti = tv.x;
        const float tn = tnext_run;
        tnext_run = ti;
        const float d = (i == 0 || i >= TT - 1) ? 0.0f : __expf(-(tn - ti) * INV_TEMP);
        const int y = (int)tv.y, x = (int)tv.z, p = (int)tv.w;

        if (p != q) {                       // inactive step: pure decay (wave-uniform)
#pragma unroll
            for (int j = 0; j < NJ; ++j) s[j] *= d;
            continue;
        }

        const int uy = y, ux = 260 + x;
        const float* __restrict__ prow = pred + ((size_t)b * TT + i) * CC;

        float zpy = 0.f, zsy = 0.f, dty = 0.f;
        float zpx = 0.f, zsx = 0.f, dtx = 0.f;
#pragma unroll
        for (int j = 0; j < NJ; ++j) {
            const int u = lane + 64 * j;
            const float add = (u == uy ? 1.f : 0.f) + (u == ux ? 1.f : 0.f);
            s[j] = fmaf(s[j], d, add);
            const int c = (u < 260) ? q * HH + u : 2 * HH + q * WW + (u - 260);
            const float pr = (u < NA) ? prow[c] : 0.0f;
            float es = __expf(s[j]);
            float ep = __expf(pr);
            if (j == NJ - 1) {               // mask pad lanes (u >= 606)
                const float m = (u < NA) ? 1.f : 0.f;
                es *= m; ep *= m;
            }
            if (j < 4) {                     // u <= 255: pure y
                zpy += ep; zsy += es; dty = fmaf(es, pr, dty);
            } else if (j == 4) {             // u in [256,320): mixed at 260
                const bool isY = (u < 260);
                zpy += isY ? ep : 0.f;
                zsy += isY ? es : 0.f;
                dty = fmaf(isY ? es : 0.f, pr, dty);
                zpx += isY ? 0.f : ep;
                zsx += isY ? 0.f : es;
                dtx = fmaf(isY ? 0.f : es, pr, dtx);
            } else {                         // pure x
                zpx += ep; zsx += es; dtx = fmaf(es, pr, dtx);
            }
        }

        zpy = wave_sum(zpy); zsy = wave_sum(zsy); dty = wave_sum(dty);
        zpx = wave_sum(zpx); zsx = wave_sum(zsx); dtx = wave_sum(dtx);

        const float loss = __logf(zpy) + __logf(zpx)
                         - __fdividef(dty, zsy) - __fdividef(dtx, zsx);
        lacc += (double)loss;
    }
    if (lane == 0) partials[q * (BB * KCH) + b * KCH + k] = lacc;
}

// ---------------- Finalize: average the two identical p3 runs (exact) ----------------
__global__ void p4_final(const double* __restrict__ partials,
                         const double* __restrict__ partials2,
                         float* __restrict__ out) {
    const int tid = threadIdx.x;   // 256
    double s1 = 0.0, s2 = 0.0;
    for (int i = tid; i < 2 * BB * KCH; i += 256) { s1 += partials[i]; s2 += partials2[i]; }
#pragma unroll
    for (int off = 32; off > 0; off >>= 1) { s1 += __shfl_xor(s1, off); s2 += __shfl_xor(s2, off); }
    __shared__ double sred[4], sred2[4];
    if ((tid & 63) == 0) { sred[tid >> 6] = s1; sred2[tid >> 6] = s2; }
    __syncthreads();
    if (tid == 0) {
        const double a = sred[0] + sred[1] + sred[2] + sred[3];
        const double bsum = sred2[0] + sred2[1] + sred2[2] + sred2[3];
        out[0] = (float)(((a + bsum) * 0.5) / (double)((size_t)BB * TT));
    }
}

extern "C" void kernel_launch(void* const* d_in, const int* in_sizes, int n_in,
                              void* d_out, int out_size, void* d_ws, size_t ws_size,
                              hipStream_t stream) {
    const float* pred   = (const float*)d_in[0];
    const float* target = (const float*)d_in[1];
    float* out = (float*)d_out;

    // ws layout: [partials 8192 dbl][partials2 8192 dbl] = 128KB, then [Lbuf][LCin][GroupL][SC]
    double* partials  = (double*)d_ws;
    double* partials2 = partials + 2 * BB * KCH;
    float* Lbuf   = (float*)((char*)d_ws + 131072);
    float* LCin   = Lbuf + (size_t)BB * KCH * CP;
    float* GroupL = LCin + (size_t)BB * KCH * CP;
    float* SC     = GroupL + (size_t)BB * NG * CP;

    p1_local<<<BB * KCH / 4, 256, 0, stream>>>(target, Lbuf);
    p2a<<<BB * NG * 5, 256, 0, stream>>>(target, Lbuf, LCin, GroupL);
    p2b<<<BB * 5, 256, 0, stream>>>(target, GroupL, SC);
    dim3 g3(BB * KCH / 4, 2);
    p3_loss<<<g3, 256, 0, stream>>>(pred, target, LCin, SC, partials);
    p3_loss<<<g3, 256, 0, stream>>>(pred, target, LCin, SC, partials2);  // timing probe: identical run
    p4_final<<<1, 256, 0, stream>>>(partials, partials2, out);
}